// Round 3
// baseline (219.479 us; speedup 1.0000x reference)
//
#include <hip/hip_runtime.h>

// SABR IV surface, specialized for BETA=1, R=Q=0, RHO=-0.7, VOLVOL=0.3.
// With BETA=1: x=1, A=v, F=p, logFK=-log(m) -> output independent of price.
// out[i,j,t,m] = v*B(t)                      if m==1.0
//              = v*B(t)*Phi(m)/(Chi(m)+1e-8) otherwise
// B(t) = 1 + t*(c1*v + c2), Phi = 0.3*(-log m)/v,
// Chi = log((sqrt(1 + 1.4*Phi + Phi^2) + Phi + 0.7)/1.7)
//
// R3: same as R2 but with a native clang ext_vector_type for the
// nontemporal 16B stores (HIP's float4 class is rejected by the builtin).

#define THREADS 256
#define VALS_PER_PAIR 25

typedef float floatx4 __attribute__((ext_vector_type(4)));

__device__ __forceinline__ float fast_ln(float x) {
    // v_log_f32 gives log2(x); scale by ln(2)
    return __builtin_amdgcn_logf(x) * 0.6931471805599453f;
}

__global__ __launch_bounds__(THREADS)
void sabr_kernel(const float* __restrict__ vol, float* __restrict__ out) {
    __shared__ float sm[THREADS * VALS_PER_PAIR];  // 25.6 KB

    const int tid   = threadIdx.x;
    const int pair0 = blockIdx.x * THREADS;
    const float v   = vol[pair0 + tid];

    // Constants
    const float c1 = -0.0525f;                       // RHO*VOLVOL/4
    const float c2 = 0.09f * 0.53f / 24.0f;          // VOLVOL^2*(2-3*RHO^2)/24
    // cPhi[m] = VOLVOL * (-log(m)); m = {0.7, 0.85, 1.0, 1.15, 1.3}
    const float cPhi[5] = { 0.3f * 0.35667494393873245f,
                            0.3f * 0.1625189294977749f,
                            0.0f,
                            0.3f * -0.13976194237515863f,
                            0.3f * -0.26236426446749106f };

    float g[5];
    const float inv_v = __builtin_amdgcn_rcpf(v);
#pragma unroll
    for (int mi = 0; mi < 5; ++mi) {
        if (mi == 2) { g[2] = 1.0f; continue; }
        const float Phi = cPhi[mi] * inv_v;
        const float arg = (__builtin_amdgcn_sqrtf(1.0f + 1.4f * Phi + Phi * Phi)
                           + Phi + 0.7f) * (1.0f / 1.7f);
        const float Chi = fast_ln(arg);
        g[mi] = Phi * __builtin_amdgcn_rcpf(Chi + 1e-8f);
    }

    const float slope = c1 * v + c2;
#pragma unroll
    for (int ti = 0; ti < 5; ++ti) {
        const float vB = v * (1.0f + (float)ti * slope);
#pragma unroll
        for (int mi = 0; mi < 5; ++mi) {
            sm[tid * VALS_PER_PAIR + ti * 5 + mi] = vB * g[mi];
        }
    }

    __syncthreads();

    // Block's output range is contiguous: THREADS*25 = 6400 floats = 1600 x 16B
    floatx4* __restrict__ out4 = (floatx4*)(out + (size_t)pair0 * VALS_PER_PAIR);
    const floatx4* __restrict__ sm4 = (const floatx4*)sm;
#pragma unroll
    for (int k = tid; k < (THREADS * VALS_PER_PAIR) / 4; k += THREADS) {
        __builtin_nontemporal_store(sm4[k], &out4[k]);
    }
}

extern "C" void kernel_launch(void* const* d_in, const int* in_sizes, int n_in,
                              void* d_out, int out_size, void* d_ws, size_t ws_size,
                              hipStream_t stream) {
    const float* vol = (const float*)d_in[0];
    // d_in[1] (price) is unused: with BETA=1 and R=Q=0 the output is price-independent.
    float* out = (float*)d_out;
    const int npair = in_sizes[0];          // 4096*512 = 2097152
    const int grid  = npair / THREADS;      // 8192 blocks
    sabr_kernel<<<grid, THREADS, 0, stream>>>(vol, out);
}

// Round 4
// 211.727 us; speedup vs baseline: 1.0366x; 1.0366x over previous
//
#include <hip/hip_runtime.h>

// SABR IV surface, specialized for BETA=1, R=Q=0, RHO=-0.7, VOLVOL=0.3.
// With BETA=1: x=1, A=v, F=p, logFK=-log(m) -> output independent of price.
// out[i,j,t,m] = v*B(t)                      if m==1.0
//              = v*B(t)*Phi(m)/(Chi(m)+1e-8) otherwise
// B(t) = 1 + t*(c1*v + c2), Phi = 0.3*(-log m)/v,
// Chi = log((sqrt(1 + 1.4*Phi + Phi^2) + Phi + 0.7)/1.7)
//
// R4: plain float4 stores (nontemporal cost +7us in R3 -- L2 write-combining
// wants the normal path). Intrinsic math kept: compute is ~1.4us total
// (32K waves x 13 transc x 8cyc / 1024 SIMDs), kernel is store-bound.

#define THREADS 256
#define VALS_PER_PAIR 25

__device__ __forceinline__ float fast_ln(float x) {
    // v_log_f32 gives log2(x); scale by ln(2)
    return __builtin_amdgcn_logf(x) * 0.6931471805599453f;
}

__global__ __launch_bounds__(THREADS)
void sabr_kernel(const float* __restrict__ vol, float* __restrict__ out) {
    __shared__ float sm[THREADS * VALS_PER_PAIR];  // 25.6 KB -> 6 blocks/CU

    const int tid   = threadIdx.x;
    const int pair0 = blockIdx.x * THREADS;
    const float v   = vol[pair0 + tid];

    // Constants
    const float c1 = -0.0525f;                       // RHO*VOLVOL/4
    const float c2 = 0.09f * 0.53f / 24.0f;          // VOLVOL^2*(2-3*RHO^2)/24
    // cPhi[m] = VOLVOL * (-log(m)); m = {0.7, 0.85, 1.0, 1.15, 1.3}
    const float cPhi[5] = { 0.3f * 0.35667494393873245f,
                            0.3f * 0.1625189294977749f,
                            0.0f,
                            0.3f * -0.13976194237515863f,
                            0.3f * -0.26236426446749106f };

    float g[5];
    const float inv_v = __builtin_amdgcn_rcpf(v);
#pragma unroll
    for (int mi = 0; mi < 5; ++mi) {
        if (mi == 2) { g[2] = 1.0f; continue; }
        const float Phi = cPhi[mi] * inv_v;
        const float arg = (__builtin_amdgcn_sqrtf(1.0f + 1.4f * Phi + Phi * Phi)
                           + Phi + 0.7f) * (1.0f / 1.7f);
        const float Chi = fast_ln(arg);
        g[mi] = Phi * __builtin_amdgcn_rcpf(Chi + 1e-8f);
    }

    const float slope = c1 * v + c2;
#pragma unroll
    for (int ti = 0; ti < 5; ++ti) {
        const float vB = v * (1.0f + (float)ti * slope);
#pragma unroll
        for (int mi = 0; mi < 5; ++mi) {
            sm[tid * VALS_PER_PAIR + ti * 5 + mi] = vB * g[mi];
        }
    }

    __syncthreads();

    // Block's output range is contiguous: THREADS*25 = 6400 floats = 1600 float4
    float4* __restrict__ out4 = (float4*)(out + (size_t)pair0 * VALS_PER_PAIR);
    const float4* __restrict__ sm4 = (const float4*)sm;
#pragma unroll
    for (int k = tid; k < (THREADS * VALS_PER_PAIR) / 4; k += THREADS) {
        out4[k] = sm4[k];
    }
}

extern "C" void kernel_launch(void* const* d_in, const int* in_sizes, int n_in,
                              void* d_out, int out_size, void* d_ws, size_t ws_size,
                              hipStream_t stream) {
    const float* vol = (const float*)d_in[0];
    // d_in[1] (price) is unused: with BETA=1 and R=Q=0 the output is price-independent.
    float* out = (float*)d_out;
    const int npair = in_sizes[0];          // 4096*512 = 2097152
    const int grid  = npair / THREADS;      // 8192 blocks
    sabr_kernel<<<grid, THREADS, 0, stream>>>(vol, out);
}

// Round 5
// 211.254 us; speedup vs baseline: 1.0389x; 1.0022x over previous
//
#include <hip/hip_runtime.h>

// SABR IV surface, specialized for BETA=1, R=Q=0, RHO=-0.7, VOLVOL=0.3.
// With BETA=1: x=1, A=v, F=p, logFK=-log(m) -> output independent of price.
// out[i,j,t,m] = v*B(t)                      if m==1.0
//              = v*B(t)*Phi(m)/(Chi(m)+1e-8) otherwise
// B(t) = 1 + t*(c1*v + c2), Phi = 0.3*(-log m)/v,
// Chi = log((sqrt(1 + 1.4*Phi + Phi^2) + Phi + 0.7)/1.7)
//
// R5: wave-private LDS transpose, NO __syncthreads. Each wave transposes its
// 64 pairs through its own 6.4 KB LDS slice (only lgkmcnt ordering needed),
// so each wave flows compute->store independently -- removes the block-wide
// barrier convoy that left store-issue bubbles (kernel ~50us vs 33us write
// floor in R4). Plain float4 stores (nt regressed +7us in R3).

#define THREADS 256
#define VALS_PER_PAIR 25
#define WAVE 64

__device__ __forceinline__ float fast_ln(float x) {
    // v_log_f32 gives log2(x); scale by ln(2)
    return __builtin_amdgcn_logf(x) * 0.6931471805599453f;
}

__global__ __launch_bounds__(THREADS)
void sabr_kernel(const float* __restrict__ vol, float* __restrict__ out) {
    __shared__ float sm[THREADS * VALS_PER_PAIR];  // 25.6 KB -> 6 blocks/CU

    const int tid   = threadIdx.x;
    const int wave  = tid >> 6;
    const int lane  = tid & 63;
    const int pair0 = blockIdx.x * THREADS;
    const float v   = vol[pair0 + tid];

    // wave-private LDS slice: 64 pairs * 25 vals = 1600 floats
    float* smw = sm + wave * (WAVE * VALS_PER_PAIR);

    // Constants
    const float c1 = -0.0525f;                       // RHO*VOLVOL/4
    const float c2 = 0.09f * 0.53f / 24.0f;          // VOLVOL^2*(2-3*RHO^2)/24
    // cPhi[m] = VOLVOL * (-log(m)); m = {0.7, 0.85, 1.0, 1.15, 1.3}
    const float cPhi[5] = { 0.3f * 0.35667494393873245f,
                            0.3f * 0.1625189294977749f,
                            0.0f,
                            0.3f * -0.13976194237515863f,
                            0.3f * -0.26236426446749106f };

    float g[5];
    const float inv_v = __builtin_amdgcn_rcpf(v);
#pragma unroll
    for (int mi = 0; mi < 5; ++mi) {
        if (mi == 2) { g[2] = 1.0f; continue; }
        const float Phi = cPhi[mi] * inv_v;
        const float arg = (__builtin_amdgcn_sqrtf(1.0f + 1.4f * Phi + Phi * Phi)
                           + Phi + 0.7f) * (1.0f / 1.7f);
        const float Chi = fast_ln(arg);
        g[mi] = Phi * __builtin_amdgcn_rcpf(Chi + 1e-8f);
    }

    const float slope = c1 * v + c2;
#pragma unroll
    for (int ti = 0; ti < 5; ++ti) {
        const float vB = v * (1.0f + (float)ti * slope);
#pragma unroll
        for (int mi = 0; mi < 5; ++mi) {
            smw[lane * VALS_PER_PAIR + ti * 5 + mi] = vB * g[mi];
        }
    }
    // No __syncthreads: each wave reads only its own LDS slice; the compiler's
    // lgkmcnt wait orders the wave's own writes before its reads.

    // Wave's output range is contiguous: 64*25 = 1600 floats = 400 float4
    float4* __restrict__ out4 =
        (float4*)(out + (size_t)(pair0 + wave * WAVE) * VALS_PER_PAIR);
    const float4* __restrict__ sm4 = (const float4*)smw;
#pragma unroll
    for (int k = lane; k < (WAVE * VALS_PER_PAIR) / 4; k += WAVE) {
        out4[k] = sm4[k];
    }
}

extern "C" void kernel_launch(void* const* d_in, const int* in_sizes, int n_in,
                              void* d_out, int out_size, void* d_ws, size_t ws_size,
                              hipStream_t stream) {
    const float* vol = (const float*)d_in[0];
    // d_in[1] (price) is unused: with BETA=1 and R=Q=0 the output is price-independent.
    float* out = (float*)d_out;
    const int npair = in_sizes[0];          // 4096*512 = 2097152
    const int grid  = npair / THREADS;      // 8192 blocks
    sabr_kernel<<<grid, THREADS, 0, stream>>>(vol, out);
}